// Round 2
// baseline (771.679 us; speedup 1.0000x reference)
//
#include <hip/hip_runtime.h>

// GIN on MI355X. Round 16 = R14 base with k_agg restructured as a
// column-split 2-pass gather (L2-residency play):
//  - y and u are stored as two 6.4MB arrays (features 0..31 / 32..63).
//  - k_agg runs twice per layer (separate launches); each pass randomly
//    gathers 64B row-chunks from ONE 6.4MB array -> ~fits per-XCD 4MB L2
//    (vs 12.8MB before, which forced every gather to ~700cy L3).
//    Line-request count unchanged (2xE requests x 1 line vs E x 2 lines).
//  - pass kernel: 4 neighbor streams x 16 lanes x 4B; 8 accumulator
//    VGPRs; launch_bounds(256,4) (non-binding; no forced spills).
//  - build / MFMA MLPs / pool write/read the split layout with
//    byte-identical LDS contents; everything else unchanged from R14.

constexpr int N   = 100000;
constexpr int E   = 1600000;
constexpr int DIN = 128;
constexpr int H   = 64;
constexpr int OUT = 16;
constexpr int G   = 512;
constexpr int SLOT = 64;

constexpr int NB_EDGES    = (E + 255) / 256;       // 6250
constexpr int NB_TILE64   = (N + 63) / 64;         // 1563
constexpr int NB_BUILD    = NB_TILE64 + NB_EDGES;  // 7813
constexpr int NB_WAVENODE = (N * 64 + 255) / 256;  // 25000

typedef __attribute__((ext_vector_type(8))) short bf16x8;
typedef __attribute__((ext_vector_type(4))) float f32x4;

__device__ __forceinline__ float bf2f(unsigned short u) {
  union { unsigned int i; float f; } v;
  v.i = ((unsigned int)u) << 16;
  return v.f;
}
__device__ __forceinline__ unsigned int f2bf(float f) {
  union { float f; unsigned int i; } v;
  v.f = f;
  unsigned int r = v.i + 0x7fff + ((v.i >> 16) & 1);  // RNE
  return r >> 16;
}

// ---- weight prep: wt[mat][n*64+k] = bf16(w[mat][k*64+n]), 9 mats 64x64. ----
__global__ void k_prep(const float* __restrict__ w2_0, const float* __restrict__ w2_r,
                       const float* __restrict__ w1_r, unsigned short* __restrict__ wt) {
  int i = blockIdx.x * 256 + threadIdx.x;
  if (i >= 9 * 4096) return;
  int mat = i >> 12, rem = i & 4095;
  int n = rem >> 6, k = rem & 63;
  const float* s;
  if (mat == 0) s = w2_0;
  else if (mat < 5) s = w2_r + (mat - 1) * 4096;
  else s = w1_r + (mat - 5) * 4096;
  wt[i] = (unsigned short)f2bf(s[k * 64 + n]);
}

// ---- fused build: interleaved roles. blockIdx%5==0 -> gemm tile. ----
__global__ __launch_bounds__(256, 4) void k_build_gemm(const int* __restrict__ src,
                                                       const int* __restrict__ dst,
                                                       int* __restrict__ deg,
                                                       int* __restrict__ slots,
                                                       const float* __restrict__ x,
                                                       const float* __restrict__ w1,
                                                       unsigned int* __restrict__ ylo,
                                                       unsigned int* __restrict__ yhi) {
  __shared__ unsigned int sx[64 * 65];
  int t = threadIdx.x;
  int b = blockIdx.x;
  int q5 = b / 5;
  if (b - q5 * 5 != 0) {
    int e = (b - q5 - 1) * 256 + t;
    if (e < E) {
      int s = src[e];
      int d = dst[e];
      int p = atomicAdd(&deg[d], 1);
      if (p < SLOT) __builtin_nontemporal_store(s, &slots[(size_t)d * SLOT + p]);
    }
    return;
  }
  int nb = q5 * 64;
  int rows = min(64, N - nb);
#pragma unroll
  for (int it = 0; it < 8; ++it) {
    int idx4 = it * 256 + t;
    int r = idx4 >> 5, d4 = idx4 & 31;
    if (r < rows) {
      float4 v = ((const float4*)(x + (size_t)(nb + r) * DIN))[d4];
      sx[r * 65 + d4 * 2]     = f2bf(v.x) | (f2bf(v.y) << 16);
      sx[r * 65 + d4 * 2 + 1] = f2bf(v.z) | (f2bf(v.w) << 16);
    }
  }
  __syncthreads();
  int l = t & 63;
  int jg = __builtin_amdgcn_readfirstlane(t >> 6);
  float acc[16];
#pragma unroll
  for (int j = 0; j < 16; ++j) acc[j] = 0.f;
#pragma unroll 2
  for (int dd = 0; dd < 64; ++dd) {
    unsigned int pv = sx[l * 65 + dd];
    float vlo = bf2f((unsigned short)(pv & 0xffff));
    float vhi = bf2f((unsigned short)(pv >> 16));
    const float* wr0 = w1 + (2 * dd) * H + jg * 16;
    const float* wr1 = wr0 + H;
#pragma unroll
    for (int j = 0; j < 16; ++j) acc[j] += vlo * wr0[j] + vhi * wr1[j];
  }
  __syncthreads();
  unsigned int* so = sx;
#pragma unroll
  for (int k = 0; k < 8; ++k)
    so[l * 33 + jg * 8 + k] = f2bf(acc[2 * k]) | (f2bf(acc[2 * k + 1]) << 16);
  __syncthreads();
#pragma unroll
  for (int it = 0; it < 8; ++it) {
    int m = it * 256 + t;
    int r = m >> 5, c = m & 31;
    if (r < rows) {
      unsigned int v = so[r * 33 + c];
      if (c < 16) ylo[(size_t)(nb + r) * 16 + c] = v;
      else        yhi[(size_t)(nb + r) * 16 + (c - 16)] = v;
    }
  }
}

// ---- one column-chunk aggregation pass:
//      uc = bf16(relu(yc_self + sum_nb yc + b1c)); wave/node.
//      quad q = lane>>4 picks neighbor stream 4i+q; fl = lane&15 is the
//      uint (2 features) within the 64B chunk row. One vmem instruction
//      fetches 4 chunk-rows (4 lines). Slot indices via int4 broadcast. ----
__device__ __forceinline__ int sel4(int4 v, int q) {
  int c = v.x;
  c = (q == 1) ? v.y : c;
  c = (q == 2) ? v.z : c;
  c = (q == 3) ? v.w : c;
  return c;
}

__global__ __launch_bounds__(256, 4) void k_agg(const unsigned int* __restrict__ yc,
                                                const int* __restrict__ deg,
                                                const int* __restrict__ slots,
                                                const float* __restrict__ b1c,
                                                unsigned int* __restrict__ uc) {
  int w = (blockIdx.x * 256 + threadIdx.x) >> 6;
  int lane = threadIdx.x & 63;
  if (w >= N) return;
  int q = lane >> 4, fl = lane & 15;
  const int4* s4 = (const int4*)(slots + (size_t)w * SLOT);
  int d = min(deg[w], SLOT);
  int dq = d >> 2, rem = d & 3;
  float a0x = 0.f, a0y = 0.f, a1x = 0.f, a1y = 0.f;
  float a2x = 0.f, a2y = 0.f, a3x = 0.f, a3y = 0.f;
  // self row-chunk (add once: stream 0 only)
  if (q == 0) {
    unsigned int sv = yc[(size_t)w * 16 + fl];
    a0x += bf2f((unsigned short)(sv & 0xffff));
    a0y += bf2f((unsigned short)(sv >> 16));
  }
  int i = 0;
  for (; i + 4 <= dq; i += 4) {
    int4 v0 = s4[i + 0];
    int4 v1 = s4[i + 1];
    int4 v2 = s4[i + 2];
    int4 v3 = s4[i + 3];
    int c0 = sel4(v0, q), c1 = sel4(v1, q), c2 = sel4(v2, q), c3 = sel4(v3, q);
    unsigned int g0 = yc[(size_t)c0 * 16 + fl];
    unsigned int g1 = yc[(size_t)c1 * 16 + fl];
    unsigned int g2 = yc[(size_t)c2 * 16 + fl];
    unsigned int g3 = yc[(size_t)c3 * 16 + fl];
    a0x += bf2f((unsigned short)(g0 & 0xffff)); a0y += bf2f((unsigned short)(g0 >> 16));
    a1x += bf2f((unsigned short)(g1 & 0xffff)); a1y += bf2f((unsigned short)(g1 >> 16));
    a2x += bf2f((unsigned short)(g2 & 0xffff)); a2y += bf2f((unsigned short)(g2 >> 16));
    a3x += bf2f((unsigned short)(g3 & 0xffff)); a3y += bf2f((unsigned short)(g3 >> 16));
  }
  if (dq & 2) {
    int4 v0 = s4[i + 0];
    int4 v1 = s4[i + 1];
    int c0 = sel4(v0, q), c1 = sel4(v1, q);
    unsigned int g0 = yc[(size_t)c0 * 16 + fl];
    unsigned int g1 = yc[(size_t)c1 * 16 + fl];
    a0x += bf2f((unsigned short)(g0 & 0xffff)); a0y += bf2f((unsigned short)(g0 >> 16));
    a1x += bf2f((unsigned short)(g1 & 0xffff)); a1y += bf2f((unsigned short)(g1 >> 16));
    i += 2;
  }
  if (dq & 1) {
    int4 v0 = s4[i];
    int c0 = sel4(v0, q);
    unsigned int g0 = yc[(size_t)c0 * 16 + fl];
    a2x += bf2f((unsigned short)(g0 & 0xffff)); a2y += bf2f((unsigned short)(g0 >> 16));
    i += 1;
  }
  if (q < rem) {
    const int* srow = (const int*)s4;
    int c0 = srow[4 * dq + q];
    unsigned int g0 = yc[(size_t)c0 * 16 + fl];
    a3x += bf2f((unsigned short)(g0 & 0xffff)); a3y += bf2f((unsigned short)(g0 >> 16));
  }
  float sx = (a0x + a1x) + (a2x + a3x);
  float sy = (a0y + a1y) + (a2y + a3y);
  sx += __shfl_xor(sx, 16); sx += __shfl_xor(sx, 32);
  sy += __shfl_xor(sy, 16); sy += __shfl_xor(sy, 32);
  if (lane < 16) {
    float2 bv = ((const float2*)b1c)[fl];
    float rx = fmaxf(sx + bv.x, 0.f);
    float ry = fmaxf(sy + bv.y, 0.f);
    uc[(size_t)w * 16 + fl] = f2bf(rx) | (f2bf(ry) << 16);
  }
}

// ---- MFMA fused: Y = (relu(U @ W2 + b2)) @ W1n. Split-layout I/O. ----
__global__ __launch_bounds__(256, 4) void k_fused(const unsigned int* __restrict__ ulo,
                                                  const unsigned int* __restrict__ uhi,
                                                  const unsigned short* __restrict__ w2t,
                                                  const float* __restrict__ b2,
                                                  const unsigned short* __restrict__ w1t,
                                                  unsigned int* __restrict__ ylo,
                                                  unsigned int* __restrict__ yhi) {
  __shared__ unsigned short sU[64 * 72];
  __shared__ unsigned short sH[64 * 72];
  int t = threadIdx.x;
  int nb = blockIdx.x * 64;
  int rows = min(64, N - nb);
  unsigned int* sU32 = (unsigned int*)sU;
#pragma unroll
  for (int it = 0; it < 8; ++it) {
    int m = it * 256 + t;
    int r = m >> 5, c = m & 31;
    if (r < rows)
      sU32[r * 36 + c] = (c < 16) ? ulo[(size_t)(nb + r) * 16 + c]
                                  : uhi[(size_t)(nb + r) * 16 + (c - 16)];
  }
  __syncthreads();
  int lane = t & 63;
  int w = __builtin_amdgcn_readfirstlane(t >> 6);
  int sub = lane & 15, quad = lane >> 4;
  f32x4 acc[4];
#pragma unroll
  for (int nt = 0; nt < 4; ++nt) {
    float bv = b2[nt * 16 + sub];
    acc[nt].x = bv; acc[nt].y = bv; acc[nt].z = bv; acc[nt].w = bv;
  }
#pragma unroll
  for (int ks = 0; ks < 2; ++ks) {
    bf16x8 a = *(const bf16x8*)&sU[(w * 16 + sub) * 72 + ks * 32 + quad * 8];
#pragma unroll
    for (int nt = 0; nt < 4; ++nt) {
      bf16x8 bb = *(const bf16x8*)&w2t[(nt * 16 + sub) * 64 + ks * 32 + quad * 8];
      acc[nt] = __builtin_amdgcn_mfma_f32_16x16x32_bf16(a, bb, acc[nt], 0, 0, 0);
    }
  }
#pragma unroll
  for (int nt = 0; nt < 4; ++nt) {
    sH[(w * 16 + quad * 4 + 0) * 72 + nt * 16 + sub] = (unsigned short)f2bf(fmaxf(acc[nt].x, 0.f));
    sH[(w * 16 + quad * 4 + 1) * 72 + nt * 16 + sub] = (unsigned short)f2bf(fmaxf(acc[nt].y, 0.f));
    sH[(w * 16 + quad * 4 + 2) * 72 + nt * 16 + sub] = (unsigned short)f2bf(fmaxf(acc[nt].z, 0.f));
    sH[(w * 16 + quad * 4 + 3) * 72 + nt * 16 + sub] = (unsigned short)f2bf(fmaxf(acc[nt].w, 0.f));
  }
  f32x4 acc2[4];
#pragma unroll
  for (int nt = 0; nt < 4; ++nt) { acc2[nt].x = 0.f; acc2[nt].y = 0.f; acc2[nt].z = 0.f; acc2[nt].w = 0.f; }
#pragma unroll
  for (int ks = 0; ks < 2; ++ks) {
    bf16x8 a = *(const bf16x8*)&sH[(w * 16 + sub) * 72 + ks * 32 + quad * 8];
#pragma unroll
    for (int nt = 0; nt < 4; ++nt) {
      bf16x8 bb = *(const bf16x8*)&w1t[(nt * 16 + sub) * 64 + ks * 32 + quad * 8];
      acc2[nt] = __builtin_amdgcn_mfma_f32_16x16x32_bf16(a, bb, acc2[nt], 0, 0, 0);
    }
  }
#pragma unroll
  for (int nt = 0; nt < 4; ++nt) {
    sU[(w * 16 + quad * 4 + 0) * 72 + nt * 16 + sub] = (unsigned short)f2bf(acc2[nt].x);
    sU[(w * 16 + quad * 4 + 1) * 72 + nt * 16 + sub] = (unsigned short)f2bf(acc2[nt].y);
    sU[(w * 16 + quad * 4 + 2) * 72 + nt * 16 + sub] = (unsigned short)f2bf(acc2[nt].z);
    sU[(w * 16 + quad * 4 + 3) * 72 + nt * 16 + sub] = (unsigned short)f2bf(acc2[nt].w);
  }
  __syncthreads();
#pragma unroll
  for (int it = 0; it < 8; ++it) {
    int m = it * 256 + t;
    int r = m >> 5, c = m & 31;
    if (r < rows) {
      unsigned int v = sU32[r * 36 + c];
      if (c < 16) ylo[(size_t)(nb + r) * 16 + c] = v;
      else        yhi[(size_t)(nb + r) * 16 + (c - 16)] = v;
    }
  }
}

// ---- layer 4: H5 = relu(U @ W2 + b2) via MFMA + segment-reduce pool ----
__global__ __launch_bounds__(256, 4) void k_last_pool(const unsigned int* __restrict__ ulo,
                                                      const unsigned int* __restrict__ uhi,
                                                      const unsigned short* __restrict__ w2t,
                                                      const float* __restrict__ b2,
                                                      const int* __restrict__ batch,
                                                      float* __restrict__ g) {
  __shared__ unsigned short sU[64 * 72];
  __shared__ float sb[64 * 65];
  __shared__ int sbatch[64];
  int t = threadIdx.x;
  int nb = blockIdx.x * 64;
  int rows = min(64, N - nb);
  unsigned int* sU32 = (unsigned int*)sU;
#pragma unroll
  for (int it = 0; it < 8; ++it) {
    int m = it * 256 + t;
    int r = m >> 5, c = m & 31;
    if (r < rows)
      sU32[r * 36 + c] = (c < 16) ? ulo[(size_t)(nb + r) * 16 + c]
                                  : uhi[(size_t)(nb + r) * 16 + (c - 16)];
  }
  if (t < 64) sbatch[t] = batch[min(nb + t, N - 1)];
  __syncthreads();
  int lane = t & 63;
  int w = __builtin_amdgcn_readfirstlane(t >> 6);
  int sub = lane & 15, quad = lane >> 4;
  f32x4 acc[4];
#pragma unroll
  for (int nt = 0; nt < 4; ++nt) {
    float bv = b2[nt * 16 + sub];
    acc[nt].x = bv; acc[nt].y = bv; acc[nt].z = bv; acc[nt].w = bv;
  }
#pragma unroll
  for (int ks = 0; ks < 2; ++ks) {
    bf16x8 a = *(const bf16x8*)&sU[(w * 16 + sub) * 72 + ks * 32 + quad * 8];
#pragma unroll
    for (int nt = 0; nt < 4; ++nt) {
      bf16x8 bb = *(const bf16x8*)&w2t[(nt * 16 + sub) * 64 + ks * 32 + quad * 8];
      acc[nt] = __builtin_amdgcn_mfma_f32_16x16x32_bf16(a, bb, acc[nt], 0, 0, 0);
    }
  }
#pragma unroll
  for (int nt = 0; nt < 4; ++nt) {
    sb[(w * 16 + quad * 4 + 0) * 65 + nt * 16 + sub] = fmaxf(acc[nt].x, 0.f);
    sb[(w * 16 + quad * 4 + 1) * 65 + nt * 16 + sub] = fmaxf(acc[nt].y, 0.f);
    sb[(w * 16 + quad * 4 + 2) * 65 + nt * 16 + sub] = fmaxf(acc[nt].z, 0.f);
    sb[(w * 16 + quad * 4 + 3) * 65 + nt * 16 + sub] = fmaxf(acc[nt].w, 0.f);
  }
  __syncthreads();
  int d = t & 63;
  int q = t >> 6;
  int r0 = q * 16;
  int bprev = sbatch[r0];
  float acc1 = 0.f;
#pragma unroll 4
  for (int r = 0; r < 16; ++r) {
    int row = r0 + r;
    if (row >= rows) break;
    int b = sbatch[row];
    if (b != bprev) {
      __hip_atomic_fetch_add(&g[(size_t)bprev * H + d], acc1,
                             __ATOMIC_RELAXED, __HIP_MEMORY_SCOPE_AGENT);
      acc1 = 0.f;
      bprev = b;
    }
    acc1 += sb[row * 65 + d];
  }
  if (r0 < rows)
    __hip_atomic_fetch_add(&g[(size_t)bprev * H + d], acc1,
                           __ATOMIC_RELAXED, __HIP_MEMORY_SCOPE_AGENT);
}

// out[n] = relu(g[n] @ mw1 + mb1) @ mw2 + mb2
__global__ void k_readout(const float* __restrict__ g, const float* __restrict__ mw1,
                          const float* __restrict__ mb1, const float* __restrict__ mw2,
                          const float* __restrict__ mb2, float* __restrict__ out) {
  int n = blockIdx.x * 64 + threadIdx.x;
  if (n >= G) return;
  float acc[H];
#pragma unroll
  for (int j = 0; j < H; ++j) acc[j] = mb1[j];
  const float* gr = g + (size_t)n * H;
  for (int d = 0; d < H; ++d) {
    float gd = gr[d];
    const float* wr = mw1 + d * H;
#pragma unroll
    for (int j = 0; j < H; ++j) acc[j] += gd * wr[j];
  }
#pragma unroll
  for (int j = 0; j < H; ++j) acc[j] = fmaxf(acc[j], 0.f);
  float o[OUT];
#pragma unroll
  for (int tt = 0; tt < OUT; ++tt) o[tt] = mb2[tt];
  for (int d = 0; d < H; ++d) {
    float hd = acc[d];
    const float* wr = mw2 + d * OUT;
#pragma unroll
    for (int tt = 0; tt < OUT; ++tt) o[tt] += hd * wr[tt];
  }
#pragma unroll
  for (int tt = 0; tt < OUT; ++tt) out[(size_t)n * OUT + tt] = o[tt];
}

extern "C" void kernel_launch(void* const* d_in, const int* in_sizes, int n_in,
                              void* d_out, int out_size, void* d_ws, size_t ws_size,
                              hipStream_t stream) {
  const float* x     = (const float*)d_in[0];
  const int*   ei    = (const int*)d_in[1];
  const int*   batch = (const int*)d_in[2];
  const float* w1_0  = (const float*)d_in[3];
  const float* b1_0  = (const float*)d_in[4];
  const float* w2_0  = (const float*)d_in[5];
  const float* b2_0  = (const float*)d_in[6];
  const float* w1_r  = (const float*)d_in[7];
  const float* b1_r  = (const float*)d_in[8];
  const float* w2_r  = (const float*)d_in[9];
  const float* b2_r  = (const float*)d_in[10];
  const float* mw1   = (const float*)d_in[11];
  const float* mb1   = (const float*)d_in[12];
  const float* mw2   = (const float*)d_in[13];
  const float* mb2   = (const float*)d_in[14];
  float* out = (float*)d_out;

  const int* src = ei;
  const int* dst = ei + E;

  char* ws = (char*)d_ws;
  size_t off = 0;
  auto alloc = [&](size_t bytes) -> void* {
    void* p = ws + off;
    off = (off + bytes + 255) & ~(size_t)255;
    return p;
  };
  unsigned int* ylo = (unsigned int*)alloc((size_t)N * 16 * 4);
  unsigned int* yhi = (unsigned int*)alloc((size_t)N * 16 * 4);
  unsigned int* ulo = (unsigned int*)alloc((size_t)N * 16 * 4);
  unsigned int* uhi = (unsigned int*)alloc((size_t)N * 16 * 4);
  int* deg    = (int*)alloc((size_t)N * 4);
  int* slots  = (int*)alloc((size_t)N * SLOT * 4);
  float* gbuf = (float*)alloc((size_t)G * H * 4);
  unsigned short* wt = (unsigned short*)alloc((size_t)9 * 4096 * 2);

  hipMemsetAsync(deg, 0, (size_t)N * 4, stream);
  hipMemsetAsync(gbuf, 0, (size_t)G * H * 4, stream);

  k_prep<<<144, 256, 0, stream>>>(w2_0, w2_r, w1_r, wt);
  k_build_gemm<<<NB_BUILD, 256, 0, stream>>>(src, dst, deg, slots, x, w1_0,
                                             ylo, yhi);

  unsigned short* w2t0 = wt;
  unsigned short* w2tr = wt + 4096;
  unsigned short* w1tr = wt + 5 * 4096;

  k_agg<<<NB_WAVENODE, 256, 0, stream>>>(ylo, deg, slots, b1_0, ulo);
  k_agg<<<NB_WAVENODE, 256, 0, stream>>>(yhi, deg, slots, b1_0 + 32, uhi);
  k_fused<<<NB_TILE64, 256, 0, stream>>>(ulo, uhi, w2t0, b2_0, w1tr, ylo, yhi);
  for (int i = 0; i < 3; ++i) {
    k_agg<<<NB_WAVENODE, 256, 0, stream>>>(ylo, deg, slots, b1_r + i * H, ulo);
    k_agg<<<NB_WAVENODE, 256, 0, stream>>>(yhi, deg, slots, b1_r + i * H + 32, uhi);
    k_fused<<<NB_TILE64, 256, 0, stream>>>(ulo, uhi, w2tr + i * 4096,
                                           b2_r + i * H, w1tr + (i + 1) * 4096,
                                           ylo, yhi);
  }

  k_agg<<<NB_WAVENODE, 256, 0, stream>>>(ylo, deg, slots, b1_r + 3 * H, ulo);
  k_agg<<<NB_WAVENODE, 256, 0, stream>>>(yhi, deg, slots, b1_r + 3 * H + 32, uhi);
  k_last_pool<<<NB_TILE64, 256, 0, stream>>>(ulo, uhi, w2tr + 3 * 4096,
                                             b2_r + 3 * H, batch, gbuf);

  k_readout<<<8, 64, 0, stream>>>(gbuf, mw1, mb1, mw2, mb2, out);
}

// Round 4
// 588.443 us; speedup vs baseline: 1.3114x; 1.3114x over previous
//
#include <hip/hip_runtime.h>

// GIN on MI355X. Round 18 = resubmit of R17 (previous bench was an infra
// container failure, not a kernel verdict). Exact R14 base (best measured
// 590.75us) with ONE change: k_agg's y-row gather loads are agent-scope
// (__hip_atomic_load relaxed -> global_load_dword sc0/sc1) -> not served or
// tracked by the 32KB non-coherent L1, freeing its small miss-queue (the
// suspected ~25 outstanding-lines/CU concurrency cap for this random
// 12.8MB gather). y keeps normal L2/L3 allocation. Everything else
// byte-identical to R14.

constexpr int N   = 100000;
constexpr int E   = 1600000;
constexpr int DIN = 128;
constexpr int H   = 64;
constexpr int OUT = 16;
constexpr int G   = 512;
constexpr int SLOT = 64;

constexpr int NB_EDGES    = (E + 255) / 256;       // 6250
constexpr int NB_TILE64   = (N + 63) / 64;         // 1563
constexpr int NB_BUILD    = NB_TILE64 + NB_EDGES;  // 7813
constexpr int NB_WAVENODE = (N * 64 + 255) / 256;  // 25000

typedef __attribute__((ext_vector_type(8))) short bf16x8;
typedef __attribute__((ext_vector_type(4))) float f32x4;

__device__ __forceinline__ float bf2f(unsigned short u) {
  union { unsigned int i; float f; } v;
  v.i = ((unsigned int)u) << 16;
  return v.f;
}
__device__ __forceinline__ unsigned int f2bf(float f) {
  union { float f; unsigned int i; } v;
  v.f = f;
  unsigned int r = v.i + 0x7fff + ((v.i >> 16) & 1);  // RNE
  return r >> 16;
}
// agent-scope load: bypasses (and does not occupy) the non-coherent L1.
__device__ __forceinline__ unsigned int ldg_agent(const unsigned int* p) {
  return __hip_atomic_load(p, __ATOMIC_RELAXED, __HIP_MEMORY_SCOPE_AGENT);
}

// ---- weight prep: wt[mat][n*64+k] = bf16(w[mat][k*64+n]), 9 mats 64x64. ----
__global__ void k_prep(const float* __restrict__ w2_0, const float* __restrict__ w2_r,
                       const float* __restrict__ w1_r, unsigned short* __restrict__ wt) {
  int i = blockIdx.x * 256 + threadIdx.x;
  if (i >= 9 * 4096) return;
  int mat = i >> 12, rem = i & 4095;
  int n = rem >> 6, k = rem & 63;
  const float* s;
  if (mat == 0) s = w2_0;
  else if (mat < 5) s = w2_r + (mat - 1) * 4096;
  else s = w1_r + (mat - 5) * 4096;
  wt[i] = (unsigned short)f2bf(s[k * 64 + n]);
}

// ---- fused build: interleaved roles. blockIdx%5==0 -> gemm tile. ----
__global__ __launch_bounds__(256, 4) void k_build_gemm(const int* __restrict__ src,
                                                       const int* __restrict__ dst,
                                                       int* __restrict__ deg,
                                                       int* __restrict__ slots,
                                                       const float* __restrict__ x,
                                                       const float* __restrict__ w1,
                                                       unsigned short* __restrict__ y) {
  __shared__ unsigned int sx[64 * 65];
  int t = threadIdx.x;
  int b = blockIdx.x;
  int q5 = b / 5;
  if (b - q5 * 5 != 0) {
    int e = (b - q5 - 1) * 256 + t;
    if (e < E) {
      int s = src[e];
      int d = dst[e];
      int p = atomicAdd(&deg[d], 1);
      if (p < SLOT) __builtin_nontemporal_store(s, &slots[(size_t)d * SLOT + p]);
    }
    return;
  }
  int nb = q5 * 64;
  int rows = min(64, N - nb);
#pragma unroll
  for (int it = 0; it < 8; ++it) {
    int idx4 = it * 256 + t;
    int r = idx4 >> 5, d4 = idx4 & 31;
    if (r < rows) {
      float4 v = ((const float4*)(x + (size_t)(nb + r) * DIN))[d4];
      sx[r * 65 + d4 * 2]     = f2bf(v.x) | (f2bf(v.y) << 16);
      sx[r * 65 + d4 * 2 + 1] = f2bf(v.z) | (f2bf(v.w) << 16);
    }
  }
  __syncthreads();
  int l = t & 63;
  int jg = __builtin_amdgcn_readfirstlane(t >> 6);
  float acc[16];
#pragma unroll
  for (int j = 0; j < 16; ++j) acc[j] = 0.f;
#pragma unroll 2
  for (int dd = 0; dd < 64; ++dd) {
    unsigned int pv = sx[l * 65 + dd];
    float vlo = bf2f((unsigned short)(pv & 0xffff));
    float vhi = bf2f((unsigned short)(pv >> 16));
    const float* wr0 = w1 + (2 * dd) * H + jg * 16;
    const float* wr1 = wr0 + H;
#pragma unroll
    for (int j = 0; j < 16; ++j) acc[j] += vlo * wr0[j] + vhi * wr1[j];
  }
  __syncthreads();
  unsigned int* so = sx;
#pragma unroll
  for (int k = 0; k < 8; ++k)
    so[l * 33 + jg * 8 + k] = f2bf(acc[2 * k]) | (f2bf(acc[2 * k + 1]) << 16);
  __syncthreads();
  unsigned int* yo = (unsigned int*)y;
#pragma unroll
  for (int it = 0; it < 8; ++it) {
    int m = it * 256 + t;
    int r = m >> 5, c = m & 31;
    if (r < rows) yo[(size_t)(nb + r) * 32 + c] = so[r * 33 + c];
  }
}

// ---- u = bf16(relu(y + A*y + b1)); wave/node; dual-row gathers:
//      half = lane>>5 (even/odd neighbor stream), fl = lane&31 (2 features).
//      8 vmem instrs in flight x 2 rows each = 16 lines in flight.
//      Gathers are agent-scope (sc0): skip L1 + its miss-queue. ----
__global__ void k_agg(const unsigned short* __restrict__ y, const int* __restrict__ deg,
                      const int* __restrict__ slots, const float* __restrict__ b1,
                      unsigned short* __restrict__ u) {
  int w = (blockIdx.x * 256 + threadIdx.x) >> 6;
  int lane = threadIdx.x & 63;
  if (w >= N) return;
  int half = lane >> 5, fl = lane & 31;
  const unsigned int* y32 = (const unsigned int*)y;
  const int* srow = slots + (size_t)w * SLOT;
  int d = min(deg[w], SLOT);
  int dp = d >> 1;  // neighbor pairs; position 2i+half belongs to this half
  float ax0 = 0.f, ay0 = 0.f, ax1 = 0.f, ay1 = 0.f;
  float ax2 = 0.f, ay2 = 0.f, ax3 = 0.f, ay3 = 0.f;
  float ax4 = 0.f, ay4 = 0.f, ax5 = 0.f, ay5 = 0.f;
  float ax6 = 0.f, ay6 = 0.f, ax7 = 0.f, ay7 = 0.f;
  // self row (add once: half 0 only)
  unsigned int sv = ldg_agent(&y32[(size_t)w * 32 + fl]);
  if (half == 0) {
    ax0 += bf2f((unsigned short)(sv & 0xffff));
    ay0 += bf2f((unsigned short)(sv >> 16));
  }
  int i = 0;
  for (; i + 8 <= dp; i += 8) {
    int c0 = srow[2 * (i + 0) + half], c1 = srow[2 * (i + 1) + half];
    int c2 = srow[2 * (i + 2) + half], c3 = srow[2 * (i + 3) + half];
    int c4 = srow[2 * (i + 4) + half], c5 = srow[2 * (i + 5) + half];
    int c6 = srow[2 * (i + 6) + half], c7 = srow[2 * (i + 7) + half];
    unsigned int g0 = ldg_agent(&y32[(size_t)c0 * 32 + fl]);
    unsigned int g1 = ldg_agent(&y32[(size_t)c1 * 32 + fl]);
    unsigned int g2 = ldg_agent(&y32[(size_t)c2 * 32 + fl]);
    unsigned int g3 = ldg_agent(&y32[(size_t)c3 * 32 + fl]);
    unsigned int g4 = ldg_agent(&y32[(size_t)c4 * 32 + fl]);
    unsigned int g5 = ldg_agent(&y32[(size_t)c5 * 32 + fl]);
    unsigned int g6 = ldg_agent(&y32[(size_t)c6 * 32 + fl]);
    unsigned int g7 = ldg_agent(&y32[(size_t)c7 * 32 + fl]);
    ax0 += bf2f((unsigned short)(g0 & 0xffff)); ay0 += bf2f((unsigned short)(g0 >> 16));
    ax1 += bf2f((unsigned short)(g1 & 0xffff)); ay1 += bf2f((unsigned short)(g1 >> 16));
    ax2 += bf2f((unsigned short)(g2 & 0xffff)); ay2 += bf2f((unsigned short)(g2 >> 16));
    ax3 += bf2f((unsigned short)(g3 & 0xffff)); ay3 += bf2f((unsigned short)(g3 >> 16));
    ax4 += bf2f((unsigned short)(g4 & 0xffff)); ay4 += bf2f((unsigned short)(g4 >> 16));
    ax5 += bf2f((unsigned short)(g5 & 0xffff)); ay5 += bf2f((unsigned short)(g5 >> 16));
    ax6 += bf2f((unsigned short)(g6 & 0xffff)); ay6 += bf2f((unsigned short)(g6 >> 16));
    ax7 += bf2f((unsigned short)(g7 & 0xffff)); ay7 += bf2f((unsigned short)(g7 >> 16));
  }
  if (dp & 4) {
    int c0 = srow[2 * (i + 0) + half], c1 = srow[2 * (i + 1) + half];
    int c2 = srow[2 * (i + 2) + half], c3 = srow[2 * (i + 3) + half];
    unsigned int g0 = ldg_agent(&y32[(size_t)c0 * 32 + fl]);
    unsigned int g1 = ldg_agent(&y32[(size_t)c1 * 32 + fl]);
    unsigned int g2 = ldg_agent(&y32[(size_t)c2 * 32 + fl]);
    unsigned int g3 = ldg_agent(&y32[(size_t)c3 * 32 + fl]);
    ax0 += bf2f((unsigned short)(g0 & 0xffff)); ay0 += bf2f((unsigned short)(g0 >> 16));
    ax1 += bf2f((unsigned short)(g1 & 0xffff)); ay1 += bf2f((unsigned short)(g1 >> 16));
    ax2 += bf2f((unsigned short)(g2 & 0xffff)); ay2 += bf2f((unsigned short)(g2 >> 16));
    ax3 += bf2f((unsigned short)(g3 & 0xffff)); ay3 += bf2f((unsigned short)(g3 >> 16));
    i += 4;
  }
  if (dp & 2) {
    int c0 = srow[2 * (i + 0) + half], c1 = srow[2 * (i + 1) + half];
    unsigned int g0 = ldg_agent(&y32[(size_t)c0 * 32 + fl]);
    unsigned int g1 = ldg_agent(&y32[(size_t)c1 * 32 + fl]);
    ax4 += bf2f((unsigned short)(g0 & 0xffff)); ay4 += bf2f((unsigned short)(g0 >> 16));
    ax5 += bf2f((unsigned short)(g1 & 0xffff)); ay5 += bf2f((unsigned short)(g1 >> 16));
    i += 2;
  }
  if (dp & 1) {
    int c0 = srow[2 * i + half];
    unsigned int g0 = ldg_agent(&y32[(size_t)c0 * 32 + fl]);
    ax6 += bf2f((unsigned short)(g0 & 0xffff)); ay6 += bf2f((unsigned short)(g0 >> 16));
  }
  if (d & 1) {  // last odd neighbor: half 0 only
    int c0 = srow[d - 1];
    if (half == 0) {
      unsigned int g0 = ldg_agent(&y32[(size_t)c0 * 32 + fl]);
      ax7 += bf2f((unsigned short)(g0 & 0xffff)); ay7 += bf2f((unsigned short)(g0 >> 16));
    }
  }
  float sxv = ((ax0 + ax1) + (ax2 + ax3)) + ((ax4 + ax5) + (ax6 + ax7));
  float syv = ((ay0 + ay1) + (ay2 + ay3)) + ((ay4 + ay5) + (ay6 + ay7));
  sxv += __shfl_xor(sxv, 32);
  syv += __shfl_xor(syv, 32);
  if (half == 0) {
    float rx = fmaxf(sxv + b1[2 * fl], 0.f);
    float ry = fmaxf(syv + b1[2 * fl + 1], 0.f);
    ((unsigned int*)u)[(size_t)w * 32 + fl] = f2bf(rx) | (f2bf(ry) << 16);
  }
}

// ---- MFMA fused: Y = (relu(U @ W2 + b2)) @ W1n. ----
__global__ __launch_bounds__(256, 4) void k_fused(const unsigned int* __restrict__ u32,
                                                  const unsigned short* __restrict__ w2t,
                                                  const float* __restrict__ b2,
                                                  const unsigned short* __restrict__ w1t,
                                                  unsigned short* __restrict__ yout) {
  __shared__ unsigned short sU[64 * 72];
  __shared__ unsigned short sH[64 * 72];
  int t = threadIdx.x;
  int nb = blockIdx.x * 64;
  int rows = min(64, N - nb);
  unsigned int* sU32 = (unsigned int*)sU;
#pragma unroll
  for (int it = 0; it < 8; ++it) {
    int m = it * 256 + t;
    int r = m >> 5, c = m & 31;
    if (r < rows) sU32[r * 36 + c] = u32[(size_t)(nb + r) * 32 + c];
  }
  __syncthreads();
  int lane = t & 63;
  int w = __builtin_amdgcn_readfirstlane(t >> 6);
  int sub = lane & 15, quad = lane >> 4;
  f32x4 acc[4];
#pragma unroll
  for (int nt = 0; nt < 4; ++nt) {
    float bv = b2[nt * 16 + sub];
    acc[nt].x = bv; acc[nt].y = bv; acc[nt].z = bv; acc[nt].w = bv;
  }
#pragma unroll
  for (int ks = 0; ks < 2; ++ks) {
    bf16x8 a = *(const bf16x8*)&sU[(w * 16 + sub) * 72 + ks * 32 + quad * 8];
#pragma unroll
    for (int nt = 0; nt < 4; ++nt) {
      bf16x8 bb = *(const bf16x8*)&w2t[(nt * 16 + sub) * 64 + ks * 32 + quad * 8];
      acc[nt] = __builtin_amdgcn_mfma_f32_16x16x32_bf16(a, bb, acc[nt], 0, 0, 0);
    }
  }
#pragma unroll
  for (int nt = 0; nt < 4; ++nt) {
    sH[(w * 16 + quad * 4 + 0) * 72 + nt * 16 + sub] = (unsigned short)f2bf(fmaxf(acc[nt].x, 0.f));
    sH[(w * 16 + quad * 4 + 1) * 72 + nt * 16 + sub] = (unsigned short)f2bf(fmaxf(acc[nt].y, 0.f));
    sH[(w * 16 + quad * 4 + 2) * 72 + nt * 16 + sub] = (unsigned short)f2bf(fmaxf(acc[nt].z, 0.f));
    sH[(w * 16 + quad * 4 + 3) * 72 + nt * 16 + sub] = (unsigned short)f2bf(fmaxf(acc[nt].w, 0.f));
  }
  f32x4 acc2[4];
#pragma unroll
  for (int nt = 0; nt < 4; ++nt) { acc2[nt].x = 0.f; acc2[nt].y = 0.f; acc2[nt].z = 0.f; acc2[nt].w = 0.f; }
#pragma unroll
  for (int ks = 0; ks < 2; ++ks) {
    bf16x8 a = *(const bf16x8*)&sH[(w * 16 + sub) * 72 + ks * 32 + quad * 8];
#pragma unroll
    for (int nt = 0; nt < 4; ++nt) {
      bf16x8 bb = *(const bf16x8*)&w1t[(nt * 16 + sub) * 64 + ks * 32 + quad * 8];
      acc2[nt] = __builtin_amdgcn_mfma_f32_16x16x32_bf16(a, bb, acc2[nt], 0, 0, 0);
    }
  }
#pragma unroll
  for (int nt = 0; nt < 4; ++nt) {
    sU[(w * 16 + quad * 4 + 0) * 72 + nt * 16 + sub] = (unsigned short)f2bf(acc2[nt].x);
    sU[(w * 16 + quad * 4 + 1) * 72 + nt * 16 + sub] = (unsigned short)f2bf(acc2[nt].y);
    sU[(w * 16 + quad * 4 + 2) * 72 + nt * 16 + sub] = (unsigned short)f2bf(acc2[nt].z);
    sU[(w * 16 + quad * 4 + 3) * 72 + nt * 16 + sub] = (unsigned short)f2bf(acc2[nt].w);
  }
  __syncthreads();
  unsigned int* yo = (unsigned int*)yout;
#pragma unroll
  for (int it = 0; it < 8; ++it) {
    int m = it * 256 + t;
    int r = m >> 5, c = m & 31;
    if (r < rows) yo[(size_t)(nb + r) * 32 + c] = sU32[r * 36 + c];
  }
}

// ---- layer 4: H5 = relu(U @ W2 + b2) via MFMA + segment-reduce pool ----
__global__ __launch_bounds__(256, 4) void k_last_pool(const unsigned int* __restrict__ u32,
                                                      const unsigned short* __restrict__ w2t,
                                                      const float* __restrict__ b2,
                                                      const int* __restrict__ batch,
                                                      float* __restrict__ g) {
  __shared__ unsigned short sU[64 * 72];
  __shared__ float sb[64 * 65];
  __shared__ int sbatch[64];
  int t = threadIdx.x;
  int nb = blockIdx.x * 64;
  int rows = min(64, N - nb);
  unsigned int* sU32 = (unsigned int*)sU;
#pragma unroll
  for (int it = 0; it < 8; ++it) {
    int m = it * 256 + t;
    int r = m >> 5, c = m & 31;
    if (r < rows) sU32[r * 36 + c] = u32[(size_t)(nb + r) * 32 + c];
  }
  if (t < 64) sbatch[t] = batch[min(nb + t, N - 1)];
  __syncthreads();
  int lane = t & 63;
  int w = __builtin_amdgcn_readfirstlane(t >> 6);
  int sub = lane & 15, quad = lane >> 4;
  f32x4 acc[4];
#pragma unroll
  for (int nt = 0; nt < 4; ++nt) {
    float bv = b2[nt * 16 + sub];
    acc[nt].x = bv; acc[nt].y = bv; acc[nt].z = bv; acc[nt].w = bv;
  }
#pragma unroll
  for (int ks = 0; ks < 2; ++ks) {
    bf16x8 a = *(const bf16x8*)&sU[(w * 16 + sub) * 72 + ks * 32 + quad * 8];
#pragma unroll
    for (int nt = 0; nt < 4; ++nt) {
      bf16x8 bb = *(const bf16x8*)&w2t[(nt * 16 + sub) * 64 + ks * 32 + quad * 8];
      acc[nt] = __builtin_amdgcn_mfma_f32_16x16x32_bf16(a, bb, acc[nt], 0, 0, 0);
    }
  }
#pragma unroll
  for (int nt = 0; nt < 4; ++nt) {
    sb[(w * 16 + quad * 4 + 0) * 65 + nt * 16 + sub] = fmaxf(acc[nt].x, 0.f);
    sb[(w * 16 + quad * 4 + 1) * 65 + nt * 16 + sub] = fmaxf(acc[nt].y, 0.f);
    sb[(w * 16 + quad * 4 + 2) * 65 + nt * 16 + sub] = fmaxf(acc[nt].z, 0.f);
    sb[(w * 16 + quad * 4 + 3) * 65 + nt * 16 + sub] = fmaxf(acc[nt].w, 0.f);
  }
  __syncthreads();
  int d = t & 63;
  int q = t >> 6;
  int r0 = q * 16;
  int bprev = sbatch[r0];
  float acc1 = 0.f;
#pragma unroll 4
  for (int r = 0; r < 16; ++r) {
    int row = r0 + r;
    if (row >= rows) break;
    int b = sbatch[row];
    if (b != bprev) {
      __hip_atomic_fetch_add(&g[(size_t)bprev * H + d], acc1,
                             __ATOMIC_RELAXED, __HIP_MEMORY_SCOPE_AGENT);
      acc1 = 0.f;
      bprev = b;
    }
    acc1 += sb[row * 65 + d];
  }
  if (r0 < rows)
    __hip_atomic_fetch_add(&g[(size_t)bprev * H + d], acc1,
                           __ATOMIC_RELAXED, __HIP_MEMORY_SCOPE_AGENT);
}

// out[n] = relu(g[n] @ mw1 + mb1) @ mw2 + mb2
__global__ void k_readout(const float* __restrict__ g, const float* __restrict__ mw1,
                          const float* __restrict__ mb1, const float* __restrict__ mw2,
                          const float* __restrict__ mb2, float* __restrict__ out) {
  int n = blockIdx.x * 64 + threadIdx.x;
  if (n >= G) return;
  float acc[H];
#pragma unroll
  for (int j = 0; j < H; ++j) acc[j] = mb1[j];
  const float* gr = g + (size_t)n * H;
  for (int d = 0; d < H; ++d) {
    float gd = gr[d];
    const float* wr = mw1 + d * H;
#pragma unroll
    for (int j = 0; j < H; ++j) acc[j] += gd * wr[j];
  }
#pragma unroll
  for (int j = 0; j < H; ++j) acc[j] = fmaxf(acc[j], 0.f);
  float o[OUT];
#pragma unroll
  for (int tt = 0; tt < OUT; ++tt) o[tt] = mb2[tt];
  for (int d = 0; d < H; ++d) {
    float hd = acc[d];
    const float* wr = mw2 + d * OUT;
#pragma unroll
    for (int tt = 0; tt < OUT; ++tt) o[tt] += hd * wr[tt];
  }
#pragma unroll
  for (int tt = 0; tt < OUT; ++tt) out[(size_t)n * OUT + tt] = o[tt];
}

extern "C" void kernel_launch(void* const* d_in, const int* in_sizes, int n_in,
                              void* d_out, int out_size, void* d_ws, size_t ws_size,
                              hipStream_t stream) {
  const float* x     = (const float*)d_in[0];
  const int*   ei    = (const int*)d_in[1];
  const int*   batch = (const int*)d_in[2];
  const float* w1_0  = (const float*)d_in[3];
  const float* b1_0  = (const float*)d_in[4];
  const float* w2_0  = (const float*)d_in[5];
  const float* b2_0  = (const float*)d_in[6];
  const float* w1_r  = (const float*)d_in[7];
  const float* b1_r  = (const float*)d_in[8];
  const float* w2_r  = (const float*)d_in[9];
  const float* b2_r  = (const float*)d_in[10];
  const float* mw1   = (const float*)d_in[11];
  const float* mb1   = (const float*)d_in[12];
  const float* mw2   = (const float*)d_in[13];
  const float* mb2   = (const float*)d_in[14];
  float* out = (float*)d_out;

  const int* src = ei;
  const int* dst = ei + E;

  char* ws = (char*)d_ws;
  size_t off = 0;
  auto alloc = [&](size_t bytes) -> void* {
    void* p = ws + off;
    off = (off + bytes + 255) & ~(size_t)255;
    return p;
  };
  unsigned short* ybuf = (unsigned short*)alloc((size_t)N * H * 2);
  unsigned short* ubuf = (unsigned short*)alloc((size_t)N * H * 2);
  int* deg    = (int*)alloc((size_t)N * 4);
  int* slots  = (int*)alloc((size_t)N * SLOT * 4);
  float* gbuf = (float*)alloc((size_t)G * H * 4);
  unsigned short* wt = (unsigned short*)alloc((size_t)9 * 4096 * 2);

  hipMemsetAsync(deg, 0, (size_t)N * 4, stream);
  hipMemsetAsync(gbuf, 0, (size_t)G * H * 4, stream);

  k_prep<<<144, 256, 0, stream>>>(w2_0, w2_r, w1_r, wt);
  k_build_gemm<<<NB_BUILD, 256, 0, stream>>>(src, dst, deg, slots, x, w1_0, ybuf);

  unsigned short* w2t0 = wt;
  unsigned short* w2tr = wt + 4096;
  unsigned short* w1tr = wt + 5 * 4096;

  k_agg<<<NB_WAVENODE, 256, 0, stream>>>(ybuf, deg, slots, b1_0, ubuf);
  k_fused<<<NB_TILE64, 256, 0, stream>>>((const unsigned int*)ubuf, w2t0, b2_0,
                                         w1tr, ybuf);
  for (int i = 0; i < 3; ++i) {
    k_agg<<<NB_WAVENODE, 256, 0, stream>>>(ybuf, deg, slots, b1_r + i * H, ubuf);
    k_fused<<<NB_TILE64, 256, 0, stream>>>((const unsigned int*)ubuf,
                                           w2tr + i * 4096, b2_r + i * H,
                                           w1tr + (i + 1) * 4096, ybuf);
  }

  k_agg<<<NB_WAVENODE, 256, 0, stream>>>(ybuf, deg, slots, b1_r + 3 * H, ubuf);
  k_last_pool<<<NB_TILE64, 256, 0, stream>>>((const unsigned int*)ubuf,
                                             w2tr + 3 * 4096, b2_r + 3 * H,
                                             batch, gbuf);

  k_readout<<<8, 64, 0, stream>>>(gbuf, mw1, mb1, mw2, mb2, out);
}